// Round 16
// baseline (88.500 us; speedup 1.0000x reference)
//
#include <hip/hip_runtime.h>
#include <math.h>

namespace {

typedef short  bf16x8 __attribute__((ext_vector_type(8)));
typedef float  f32x4  __attribute__((ext_vector_type(4)));

constexpr int B_TOTAL = 131072;
constexpr int T_STEPS = 32;
constexpr int EPW     = 32;     // elements per wave (1-wave blocks)

constexpr double dG   = 9.81;
constexpr double dM   = 0.1667;
constexpr double dCAF = 5.0 * 0.25 * dM * dG;
constexpr double dCAR = dCAF;
constexpr double dLF  = 0.09 - 0.036;
constexpr double dLR  = 0.036;
constexpr double dIZ  = 0.000267;

constexpr float A33N = (float)(-(2.0 * dCAF + 2.0 * dCAR));
constexpr float A35N = (float)(-(2.0 * dCAF * dLF - 2.0 * dCAR * dLR));
constexpr float A53N = (float)(-(2.0 * dLF * dCAF - 2.0 * dLR * dCAR));
constexpr float A55N = (float)(-(2.0 * dLF * dLF * dCAF + 2.0 * dLR * dLR * dCAR));
constexpr float ST1  = (float)(2.0 * dCAF / dM);
constexpr float ST5  = (float)(2.0 * dLF * dCAF / dIZ);
constexpr float MF   = (float)dM;
constexpr float IZF  = (float)dIZ;
constexpr float R0M  = (float)(0.05 * dG / dM);
constexpr float R1M  = (float)(0.05 * dG / dM);
constexpr float R2I  = (float)(0.05 * dG * 0.2 / dIZ);
constexpr float THR_OFF = 0.24f;
constexpr float THR_RAT = 6.98f;
constexpr float DT    = 0.01f;
constexpr float PI_F  = (float)3.14159265358979323846;
constexpr float TWOPI = (float)(2.0 * 3.14159265358979323846);
constexpr float INV2PI = (float)(1.0 / (2.0 * 3.14159265358979323846));
constexpr float TWO_LOG2E = 2.8853900817779268f;

__device__ __forceinline__ float fast_tanh(float x) {
    const float e = __builtin_amdgcn_exp2f(x * TWO_LOG2E);
    return fmaf(-2.0f, __builtin_amdgcn_rcpf(e + 1.0f), 1.0f);
}

__device__ __forceinline__ unsigned bf16_rne_u(float f) {
    unsigned u = __float_as_uint(f);
    return (u + 0x7fffu + ((u >> 16) & 1u)) >> 16;
}

__device__ __forceinline__ unsigned pk_bf16(float lo, float hi) {
    unsigned r;
    asm("v_cvt_pk_bf16_f32 %0, %1, %2" : "=v"(r) : "v"(lo), "v"(hi));
    return r;
}
__device__ __forceinline__ float bfl(unsigned p) { return __uint_as_float(p << 16); }
__device__ __forceinline__ float bfh(unsigned p) { return __uint_as_float(p & 0xffff0000u); }

union U4F { uint4 u; bf16x8 f; };

// ---- prep: A-fragments (W1 16x32) for 4 rotations x 3 split levels. (unchanged)
__global__ void prep_kernel(const float* __restrict__ w1, unsigned* __restrict__ ws) {
    const int i = threadIdx.x;
    if (i >= 256) return;
    const int p = i >> 6, L = i & 63;
    const int row = L & 15, g = L >> 4;
    const int pos = (g - p) & 3;
    unsigned hd[4], md[4], ld[4];
    #pragma unroll
    for (int d = 0; d < 4; ++d) {
        unsigned hh[2], mm[2], ll[2];
        #pragma unroll
        for (int s = 0; s < 2; ++s) {
            const float v = w1[row * 32 + pos * 8 + 2 * d + s];
            const unsigned h = bf16_rne_u(v);
            const float r1 = v - __uint_as_float(h << 16);
            const unsigned m = bf16_rne_u(r1);
            const float r2 = r1 - __uint_as_float(m << 16);
            const unsigned l = bf16_rne_u(r2);
            hh[s] = h; mm[s] = m; ll[s] = l;
        }
        hd[d] = hh[0] | (hh[1] << 16);
        md[d] = mm[0] | (mm[1] << 16);
        ld[d] = ll[0] | (ll[1] << 16);
    }
    uint4* w4 = reinterpret_cast<uint4*>(ws);
    w4[(p * 3 + 0) * 64 + L] = make_uint4(hd[0], hd[1], hd[2], hd[3]);
    w4[(p * 3 + 1) * 64 + L] = make_uint4(md[0], md[1], md[2], md[3]);
    w4[(p * 3 + 2) * 64 + L] = make_uint4(ld[0], ld[1], ld[2], ld[3]);
}

__device__ __forceinline__ int xbase(int e) { return (e * 64) ^ ((e & 7) << 4); }

// 3-level split of one timestep row -> X (hi +0, mid +2048, lo +4096)
__device__ __forceinline__ void split3_store(
    char* X, int off,
    float v0, float v1, float v2, float v3, float v4, float v5, float v6, float v7)
{
    const unsigned h0 = pk_bf16(v0, v1), h1 = pk_bf16(v2, v3);
    const unsigned h2 = pk_bf16(v4, v5), h3 = pk_bf16(v6, v7);
    const float r0 = v0 - bfl(h0), r1 = v1 - bfh(h0);
    const float r2 = v2 - bfl(h1), r3 = v3 - bfh(h1);
    const float r4 = v4 - bfl(h2), r5 = v5 - bfh(h2);
    const float r6 = v6 - bfl(h3), r7 = v7 - bfh(h3);
    const unsigned m0 = pk_bf16(r0, r1), m1 = pk_bf16(r2, r3);
    const unsigned m2 = pk_bf16(r4, r5), m3 = pk_bf16(r6, r7);
    const unsigned l0 = pk_bf16(r0 - bfl(m0), r1 - bfh(m0));
    const unsigned l1 = pk_bf16(r2 - bfl(m1), r3 - bfh(m1));
    const unsigned l2 = pk_bf16(r4 - bfl(m2), r5 - bfh(m2));
    const unsigned l3 = pk_bf16(r6 - bfl(m3), r7 - bfh(m3));
    *reinterpret_cast<uint4*>(X + off)        = make_uint4(h0, h1, h2, h3);
    *reinterpret_cast<uint4*>(X + 2048 + off) = make_uint4(m0, m1, m2, m3);
    *reinterpret_cast<uint4*>(X + 4096 + off) = make_uint4(l0, l1, l2, l3);
}

__global__ __launch_bounds__(64, 4)
void rollout_kernel(const float* __restrict__ fs,     // B x 4 x 8
                    const float* __restrict__ acts,   // B x 32 x 2
                    const unsigned* __restrict__ ws,  // A-fragments (prep)
                    const float* __restrict__ b1g,    // 16
                    const float* __restrict__ w2g,    // 3 x 16
                    const float* __restrict__ b2g,    // 3
                    const int*   __restrict__ en,     // 1
                    float*       __restrict__ out)    // B x 32 x 8
{
    __shared__ char  X[6144];             // 3 levels x 2 KB (32 elems x 64 B)
    __shared__ float abuf[EPW * 8];       // 1 KB  actions, 4 steps
    __shared__ float sbuf[EPW * 16];      // 2 KB  outputs, 2 steps
    // total ~9.2 KB -> 16 single-wave blocks/CU (4 waves/SIMD)

    const int L = threadIdx.x;
    const int g = L >> 4;                 // k-group / D-row-group (0..3)
    const int e = L & 31;                 // owned element (co-owned by L^32)
    const int h = L >> 5;                 // half: co-owner id
    const bool nb = (g & 1) != 0;         // own element's tile index (0/1)
    const size_t blk = (size_t)blockIdx.x * EPW;

    const int rnn = *en;

    // ---- loop-invariant registers (identical data to r15) ----
    bf16x8 Ah[4], Am[4], Al[4];
    {
        const uint4* w4 = reinterpret_cast<const uint4*>(ws);
        #pragma unroll
        for (int p = 0; p < 4; ++p) {
            U4F a; a.u = w4[(p * 3 + 0) * 64 + L]; Ah[p] = a.f;
            U4F b; b.u = w4[(p * 3 + 1) * 64 + L]; Am[p] = b.f;
            U4F c; c.u = w4[(p * 3 + 2) * 64 + L]; Al[p] = c.f;
        }
    }
    float b1s[4];
    #pragma unroll
    for (int r = 0; r < 4; ++r) b1s[r] = b1g[g * 4 + r];
    float w2s[3][4];
    #pragma unroll
    for (int c = 0; c < 3; ++c)
        #pragma unroll
        for (int r = 0; r < 4; ++r) w2s[c][r] = w2g[c * 16 + g * 4 + r];
    const float bias2_0 = b2g[0], bias2_1 = b2g[1], bias2_2 = b2g[2];

    // hoisted LDS offsets: 2 N-tiles (elements 0..15, 16..31)
    int roffv[2];
    #pragma unroll
    for (int n = 0; n < 2; ++n) roffv[n] = xbase(16 * n + (L & 15)) ^ (g * 16);
    const int wboff = xbase(e);

    // action staging (one float4 per lane covers 32 rows x 32 B)
    const int q0r = L >> 1, q0f = (L & 1) * 4;
    const int aw0 = q0r * 8 + (q0f ^ (q0r & 4));

    // ---- init: co-owners split the 4 history rows; both take state from row 3 ----
    float s0, s1, s2, s3, s4, s5, thr, steer;
    {
        const float4* ip = reinterpret_cast<const float4*>(fs + (blk + e) * 32);
        const float4 r3a = ip[6], r3b = ip[7];
        if (h == 0) {
            const float4 a0 = ip[0], b0 = ip[1], a1 = ip[2], b1 = ip[3];
            split3_store(X, wboff ^ 0,  a0.x, a0.y, a0.z, a0.w, b0.x, b0.y, b0.z, b0.w);
            split3_store(X, wboff ^ 16, a1.x, a1.y, a1.z, a1.w, b1.x, b1.y, b1.z, b1.w);
        } else {
            const float4 a2 = ip[4], b2 = ip[5];
            split3_store(X, wboff ^ 32, a2.x, a2.y, a2.z, a2.w, b2.x, b2.y, b2.z, b2.w);
            split3_store(X, wboff ^ 48, r3a.x, r3a.y, r3a.z, r3a.w, r3b.x, r3b.y, r3b.z, r3b.w);
        }
        s0 = r3a.x; s1 = r3a.y; s2 = r3a.z; s3 = r3a.w;
        s4 = r3b.x; s5 = r3b.y; thr = r3b.z; steer = r3b.w;
    }

    // prologue: chunk-0 action load
    float4 ga0 = *reinterpret_cast<const float4*>(&acts[(blk + q0r) * 64 + q0f]);

    const f32x4 zero4 = {0.f, 0.f, 0.f, 0.f};

    for (int tc = 0; tc < T_STEPS; tc += 4) {
        // stage in-flight actions; read own 4 steps (co-owners broadcast-read)
        *reinterpret_cast<float4*>(&abuf[aw0]) = ga0;
        const float4 av0 = *reinterpret_cast<const float4*>(&abuf[e * 8 + (0 ^ (e & 4))]);
        const float4 av1 = *reinterpret_cast<const float4*>(&abuf[e * 8 + (4 ^ (e & 4))]);
        if (tc + 4 < T_STEPS) {
            ga0 = *reinterpret_cast<const float4*>(&acts[(blk + q0r) * 64 + (tc + 4) * 2 + q0f]);
        }

        #pragma unroll
        for (int tl = 0; tl < 4; ++tl) {
            const float ax = (tl == 0) ? av0.x : (tl == 1) ? av0.z : (tl == 2) ? av1.x : av1.z;
            const float ay = (tl == 0) ? av0.y : (tl == 1) ? av0.w : (tl == 2) ? av1.y : av1.w;

            const float rev = s4 * INV2PI;
            const float sn = __builtin_amdgcn_sinf(rev);
            const float c  = __builtin_amdgcn_cosf(rev);

            const float Vx = s1 * c + s3 * sn;
            const float v3 = c * s3 - sn * s1;
            const float v5 = s5;

            const float inv_mvx  = __builtin_amdgcn_rcpf(MF * Vx);
            const float inv_izvx = __builtin_amdgcn_rcpf(IZF * Vx);
            const float a33 = A33N * inv_mvx;
            const float a35 = -Vx + A35N * inv_mvx;
            const float a53 = A53N * inv_izvx;
            const float a55 = A55N * inv_izvx;

            const float d0 = Vx;
            float       d1 = (thr - THR_OFF) * THR_RAT;
            const float d2 = v3;
            float       d3 = a33 * v3 + a35 * v5 + ST1 * steer;
            const float d4 = v5;
            float       d5 = a53 * v3 + a55 * v5 + ST5 * steer;

            if (rnn) {
                // ---- layer 1 via MFMA: 2 N-tiles x 6 compensated MFMAs ----
                f32x4 acc[2];
                #pragma unroll
                for (int n = 0; n < 2; ++n) {
                    U4F bh; bh.u = *reinterpret_cast<const uint4*>(X + roffv[n]);
                    U4F bm; bm.u = *reinterpret_cast<const uint4*>(X + 2048 + roffv[n]);
                    U4F bl; bl.u = *reinterpret_cast<const uint4*>(X + 4096 + roffv[n]);
                    f32x4 a = __builtin_amdgcn_mfma_f32_16x16x32_bf16(Ah[tl], bl.f, zero4, 0, 0, 0);
                    a = __builtin_amdgcn_mfma_f32_16x16x32_bf16(Al[tl], bh.f, a, 0, 0, 0);
                    a = __builtin_amdgcn_mfma_f32_16x16x32_bf16(Am[tl], bm.f, a, 0, 0, 0);
                    a = __builtin_amdgcn_mfma_f32_16x16x32_bf16(Am[tl], bh.f, a, 0, 0, 0);
                    a = __builtin_amdgcn_mfma_f32_16x16x32_bf16(Ah[tl], bm.f, a, 0, 0, 0);
                    acc[n] = __builtin_amdgcn_mfma_f32_16x16x32_bf16(Ah[tl], bh.f, a, 0, 0, 0);
                }
                // per-lane partials: rows g*4..g*4+3, tiles 0,1
                float p0[2], p1[2], p2[2];
                #pragma unroll
                for (int n = 0; n < 2; ++n) {
                    float q0 = 0.f, q1 = 0.f, q2 = 0.f;
                    #pragma unroll
                    for (int r = 0; r < 4; ++r) {
                        const float y = fast_tanh(acc[n][r] + b1s[r]);
                        q0 = fmaf(w2s[0][r], y, q0);
                        q1 = fmaf(w2s[1][r], y, q1);
                        q2 = fmaf(w2s[2][r], y, q2);
                    }
                    p0[n] = q0; p1[n] = q1; p2[n] = q2;
                }
                // reduce for own element's tile:
                // xor16 partner owns the OTHER tile -> everyone sends p[other];
                // received value = partner's partial for MY tile.
                // xor32 partner owns the SAME tile -> exchange summed 'a'.
                float z0, z1, z2;
                #pragma unroll
                for (int c3 = 0; c3 < 3; ++c3) {
                    const float* p = (c3 == 0) ? p0 : (c3 == 1) ? p1 : p2;
                    const float own  = nb ? p[1] : p[0];
                    const float sent = nb ? p[0] : p[1];
                    const float a = own + __shfl_xor(sent, 16, 64);
                    const float T = a + __shfl_xor(a, 32, 64);
                    if (c3 == 0) z0 = T; else if (c3 == 1) z1 = T; else z2 = T;
                }
                d1 += fast_tanh(z0 + bias2_0) * R0M;
                d3 += fast_tanh(z1 + bias2_1) * R1M;
                d5 += fast_tanh(z2 + bias2_2) * R2I;
            }

            const float ns0 = s0 + (c * d0 - sn * d2) * DT;
            const float ns1 = s1 + (c * d1 - sn * d3) * DT;
            const float ns2 = s2 + (sn * d0 + c * d2) * DT;
            const float ns3 = s3 + (sn * d1 + c * d3) * DT;
            float aa = s4 + d4 * DT + PI_F;
            aa = aa - floorf(aa * INV2PI) * TWOPI;
            const float ns4 = aa - PI_F;
            const float ns5 = s5 + d5 * DT;

            // stage outputs: co-owners write one float4 each
            const int c4b = (tl & 1) * 2;
            const float4 vout = h ? make_float4(ns4, ns5, ax, ay)
                                  : make_float4(ns0, ns1, ns2, ns3);
            *reinterpret_cast<float4*>(&sbuf[e * 16 + 4 * ((c4b + h) ^ (e & 3))]) = vout;

            if (rnn) {
                // one co-owner updates the window (values identical in both)
                if (h == 0) {
                    split3_store(X, wboff ^ (tl * 16), ns0, ns1, ns2, ns3, ns4, ns5, ax, ay);
                }
            }

            s0 = ns0; s1 = ns1; s2 = ns2; s3 = ns3;
            s4 = ns4; s5 = ns5; thr = ax; steer = ay;

            // ---- flush 2-step chunk (64 B/elem, full lines per 4-lane group) ----
            if (tl & 1) {
                const int t2 = tc + tl - 1;
                #pragma unroll
                for (int k = 0; k < 2; ++k) {
                    const int q   = k * 64 + L;
                    const int row = q >> 2;
                    const int f   = q & 3;
                    const float4 v = *reinterpret_cast<const float4*>(
                        &sbuf[row * 16 + 4 * (f ^ (row & 3))]);
                    *reinterpret_cast<float4*>(&out[(blk + row) * 256 + t2 * 8 + f * 4]) = v;
                }
            }
        }
    }
}

} // namespace

extern "C" void kernel_launch(void* const* d_in, const int* in_sizes, int n_in,
                              void* d_out, int out_size, void* d_ws, size_t ws_size,
                              hipStream_t stream) {
    const float* fs = (const float*)d_in[0];
    const float* ac = (const float*)d_in[1];
    const float* w1 = (const float*)d_in[2];
    const float* b1 = (const float*)d_in[3];
    const float* w2 = (const float*)d_in[4];
    const float* b2 = (const float*)d_in[5];
    const int*   en = (const int*)d_in[6];
    float* out = (float*)d_out;
    unsigned* ws = (unsigned*)d_ws;

    hipLaunchKernelGGL(prep_kernel, dim3(1), dim3(256), 0, stream, w1, ws);

    dim3 grid(B_TOTAL / EPW), block(64);
    hipLaunchKernelGGL(rollout_kernel, grid, block, 0, stream,
                       fs, ac, ws, b1, w2, b2, en, out);
}

// Round 17
// 84.816 us; speedup vs baseline: 1.0434x; 1.0434x over previous
//
#include <hip/hip_runtime.h>
#include <math.h>

namespace {

typedef short  bf16x8 __attribute__((ext_vector_type(8)));
typedef float  f32x4  __attribute__((ext_vector_type(4)));

constexpr int B_TOTAL = 131072;
constexpr int T_STEPS = 32;
constexpr int EPW     = 128;    // elements per 1-wave block (2 per lane)

constexpr double dG   = 9.81;
constexpr double dM   = 0.1667;
constexpr double dCAF = 5.0 * 0.25 * dM * dG;
constexpr double dCAR = dCAF;
constexpr double dLF  = 0.09 - 0.036;
constexpr double dLR  = 0.036;
constexpr double dIZ  = 0.000267;

constexpr float A33N = (float)(-(2.0 * dCAF + 2.0 * dCAR));
constexpr float A35N = (float)(-(2.0 * dCAF * dLF - 2.0 * dCAR * dLR));
constexpr float A53N = (float)(-(2.0 * dLF * dCAF - 2.0 * dLR * dCAR));
constexpr float A55N = (float)(-(2.0 * dLF * dLF * dCAF + 2.0 * dLR * dLR * dCAR));
constexpr float ST1  = (float)(2.0 * dCAF / dM);
constexpr float ST5  = (float)(2.0 * dLF * dCAF / dIZ);
constexpr float MF   = (float)dM;
constexpr float IZF  = (float)dIZ;
constexpr float R0M  = (float)(0.05 * dG / dM);
constexpr float R1M  = (float)(0.05 * dG / dM);
constexpr float R2I  = (float)(0.05 * dG * 0.2 / dIZ);
constexpr float THR_OFF = 0.24f;
constexpr float THR_RAT = 6.98f;
constexpr float DT    = 0.01f;
constexpr float PI_F  = (float)3.14159265358979323846;
constexpr float TWOPI = (float)(2.0 * 3.14159265358979323846);
constexpr float INV2PI = (float)(1.0 / (2.0 * 3.14159265358979323846));
constexpr float TWO_LOG2E = 2.8853900817779268f;

__device__ __forceinline__ float fast_tanh(float x) {
    const float e = __builtin_amdgcn_exp2f(x * TWO_LOG2E);
    return fmaf(-2.0f, __builtin_amdgcn_rcpf(e + 1.0f), 1.0f);
}

__device__ __forceinline__ unsigned bf16_rne_u(float f) {
    unsigned u = __float_as_uint(f);
    return (u + 0x7fffu + ((u >> 16) & 1u)) >> 16;
}

__device__ __forceinline__ unsigned pk_bf16(float lo, float hi) {
    unsigned r;
    asm("v_cvt_pk_bf16_f32 %0, %1, %2" : "=v"(r) : "v"(lo), "v"(hi));
    return r;
}
__device__ __forceinline__ float bfl(unsigned p) { return __uint_as_float(p << 16); }
__device__ __forceinline__ float bfh(unsigned p) { return __uint_as_float(p & 0xffff0000u); }

union U4F { uint4 u; bf16x8 f; };

// ---- prep: A-fragments (W1 16x32) for 4 rotations x 3 split levels. (unchanged)
__global__ void prep_kernel(const float* __restrict__ w1, unsigned* __restrict__ ws) {
    const int i = threadIdx.x;
    if (i >= 256) return;
    const int p = i >> 6, L = i & 63;
    const int row = L & 15, g = L >> 4;
    const int pos = (g - p) & 3;
    unsigned hd[4], md[4], ld[4];
    #pragma unroll
    for (int d = 0; d < 4; ++d) {
        unsigned hh[2], mm[2], ll[2];
        #pragma unroll
        for (int s = 0; s < 2; ++s) {
            const float v = w1[row * 32 + pos * 8 + 2 * d + s];
            const unsigned h = bf16_rne_u(v);
            const float r1 = v - __uint_as_float(h << 16);
            const unsigned m = bf16_rne_u(r1);
            const float r2 = r1 - __uint_as_float(m << 16);
            const unsigned l = bf16_rne_u(r2);
            hh[s] = h; mm[s] = m; ll[s] = l;
        }
        hd[d] = hh[0] | (hh[1] << 16);
        md[d] = mm[0] | (mm[1] << 16);
        ld[d] = ll[0] | (ll[1] << 16);
    }
    uint4* w4 = reinterpret_cast<uint4*>(ws);
    w4[(p * 3 + 0) * 64 + L] = make_uint4(hd[0], hd[1], hd[2], hd[3]);
    w4[(p * 3 + 1) * 64 + L] = make_uint4(md[0], md[1], md[2], md[3]);
    w4[(p * 3 + 2) * 64 + L] = make_uint4(ld[0], ld[1], ld[2], ld[3]);
}

// element byte offset within one level (e in 0..127 -> [0, 8192))
__device__ __forceinline__ int xbase(int e) { return (e * 64) ^ ((e & 7) << 4); }

// 3-level split of one timestep row -> X (hi +0, mid +8192, lo +16384)
__device__ __forceinline__ void split3_store(
    char* X, int off,
    float v0, float v1, float v2, float v3, float v4, float v5, float v6, float v7)
{
    const unsigned h0 = pk_bf16(v0, v1), h1 = pk_bf16(v2, v3);
    const unsigned h2 = pk_bf16(v4, v5), h3 = pk_bf16(v6, v7);
    const float r0 = v0 - bfl(h0), r1 = v1 - bfh(h0);
    const float r2 = v2 - bfl(h1), r3 = v3 - bfh(h1);
    const float r4 = v4 - bfl(h2), r5 = v5 - bfh(h2);
    const float r6 = v6 - bfl(h3), r7 = v7 - bfh(h3);
    const unsigned m0 = pk_bf16(r0, r1), m1 = pk_bf16(r2, r3);
    const unsigned m2 = pk_bf16(r4, r5), m3 = pk_bf16(r6, r7);
    const unsigned l0 = pk_bf16(r0 - bfl(m0), r1 - bfh(m0));
    const unsigned l1 = pk_bf16(r2 - bfl(m1), r3 - bfh(m1));
    const unsigned l2 = pk_bf16(r4 - bfl(m2), r5 - bfh(m2));
    const unsigned l3 = pk_bf16(r6 - bfl(m3), r7 - bfh(m3));
    *reinterpret_cast<uint4*>(X + off)         = make_uint4(h0, h1, h2, h3);
    *reinterpret_cast<uint4*>(X + 8192 + off)  = make_uint4(m0, m1, m2, m3);
    *reinterpret_cast<uint4*>(X + 16384 + off) = make_uint4(l0, l1, l2, l3);
}

__global__ __launch_bounds__(64, 1)
void rollout_kernel(const float* __restrict__ fs,     // B x 4 x 8
                    const float* __restrict__ acts,   // B x 32 x 2
                    const unsigned* __restrict__ ws,  // A-fragments (prep)
                    const float* __restrict__ b1g,    // 16
                    const float* __restrict__ w2g,    // 3 x 16
                    const float* __restrict__ b2g,    // 3
                    const int*   __restrict__ en,     // 1
                    float*       __restrict__ out)    // B x 32 x 8
{
    __shared__ char  X[24576];            // 3 levels x 8 KB (128 elems x 64 B)
    __shared__ float abuf[EPW * 8];       // 4 KB actions, 4 steps
    __shared__ float sbuf[EPW * 16];      // 8 KB outputs, 2 steps
    // total 36 KB -> 4 single-wave blocks/CU (1 wave/SIMD, 2 chains/lane)

    const int L = threadIdx.x;
    const int g = L >> 4;
    const size_t blk = (size_t)blockIdx.x * EPW;

    const int rnn = *en;

    // ---- loop-invariant registers (shared between both chains) ----
    bf16x8 Ah[4], Am[4], Al[4];
    {
        const uint4* w4 = reinterpret_cast<const uint4*>(ws);
        #pragma unroll
        for (int p = 0; p < 4; ++p) {
            U4F a; a.u = w4[(p * 3 + 0) * 64 + L]; Ah[p] = a.f;
            U4F b; b.u = w4[(p * 3 + 1) * 64 + L]; Am[p] = b.f;
            U4F c; c.u = w4[(p * 3 + 2) * 64 + L]; Al[p] = c.f;
        }
    }
    float b1s[4];
    #pragma unroll
    for (int r = 0; r < 4; ++r) b1s[r] = b1g[g * 4 + r];
    float w2s[3][4];
    #pragma unroll
    for (int c = 0; c < 3; ++c)
        #pragma unroll
        for (int r = 0; r < 4; ++r) w2s[c][r] = w2g[c * 16 + g * 4 + r];
    const float bias2_0 = b2g[0], bias2_1 = b2g[1], bias2_2 = b2g[2];

    // hoisted LDS offsets: 8 N-tiles (chain A: 0..3, chain B: 4..7)
    int roffv[8];
    #pragma unroll
    for (int n = 0; n < 8; ++n) roffv[n] = xbase(16 * n + (L & 15)) ^ (g * 16);
    int wboff[2];
    wboff[0] = xbase(L);
    wboff[1] = xbase(64 + L);

    // action staging addresses: k-th float4 covers rows k*32 + (L>>1)
    int ar[4], aw[4];
    #pragma unroll
    for (int k = 0; k < 4; ++k) {
        ar[k] = k * 32 + (L >> 1);
        aw[k] = ar[k] * 8 + (((L & 1) * 4) ^ (ar[k] & 4));
    }

    // ---- init: both chains' 4 history rows -> X tiles + state regs ----
    float S0[2], S1[2], S2[2], S3[2], S4[2], S5[2], TH[2], SR[2];
    #pragma unroll
    for (int ch = 0; ch < 2; ++ch) {
        const int e = ch * 64 + L;
        const float4* ip = reinterpret_cast<const float4*>(fs + (blk + e) * 32);
        #pragma unroll
        for (int rr = 0; rr < 4; ++rr) {
            const float4 va = ip[rr * 2], vb = ip[rr * 2 + 1];
            split3_store(X, wboff[ch] ^ (rr * 16), va.x, va.y, va.z, va.w, vb.x, vb.y, vb.z, vb.w);
            if (rr == 3) {
                S0[ch] = va.x; S1[ch] = va.y; S2[ch] = va.z; S3[ch] = va.w;
                S4[ch] = vb.x; S5[ch] = vb.y; TH[ch] = vb.z; SR[ch] = vb.w;
            }
        }
    }

    // prologue: chunk-0 action loads
    float4 ga0 = *reinterpret_cast<const float4*>(&acts[(blk + ar[0]) * 64 + (L & 1) * 4]);
    float4 ga1 = *reinterpret_cast<const float4*>(&acts[(blk + ar[1]) * 64 + (L & 1) * 4]);
    float4 ga2 = *reinterpret_cast<const float4*>(&acts[(blk + ar[2]) * 64 + (L & 1) * 4]);
    float4 ga3 = *reinterpret_cast<const float4*>(&acts[(blk + ar[3]) * 64 + (L & 1) * 4]);

    const f32x4 zero4 = {0.f, 0.f, 0.f, 0.f};
    const bool bb0 = (g & 1) != 0, bb1 = (g & 2) != 0;

    for (int tc = 0; tc < T_STEPS; tc += 4) {
        // stage in-flight actions; read both chains' 4 steps to regs
        *reinterpret_cast<float4*>(&abuf[aw[0]]) = ga0;
        *reinterpret_cast<float4*>(&abuf[aw[1]]) = ga1;
        *reinterpret_cast<float4*>(&abuf[aw[2]]) = ga2;
        *reinterpret_cast<float4*>(&abuf[aw[3]]) = ga3;
        float4 av0[2], av1[2];
        #pragma unroll
        for (int ch = 0; ch < 2; ++ch) {
            const int e = ch * 64 + L;
            av0[ch] = *reinterpret_cast<const float4*>(&abuf[e * 8 + (0 ^ (L & 4))]);
            av1[ch] = *reinterpret_cast<const float4*>(&abuf[e * 8 + (4 ^ (L & 4))]);
        }
        if (tc + 4 < T_STEPS) {
            ga0 = *reinterpret_cast<const float4*>(&acts[(blk + ar[0]) * 64 + (tc + 4) * 2 + (L & 1) * 4]);
            ga1 = *reinterpret_cast<const float4*>(&acts[(blk + ar[1]) * 64 + (tc + 4) * 2 + (L & 1) * 4]);
            ga2 = *reinterpret_cast<const float4*>(&acts[(blk + ar[2]) * 64 + (tc + 4) * 2 + (L & 1) * 4]);
            ga3 = *reinterpret_cast<const float4*>(&acts[(blk + ar[3]) * 64 + (tc + 4) * 2 + (L & 1) * 4]);
        }

        #pragma unroll
        for (int tl = 0; tl < 4; ++tl) {
            float AX[2], AY[2];
            float Z0[2], Z1[2], Z2[2];

            // ---- MLP for both chains (independent -> compiler interleaves) ----
            if (rnn) {
                #pragma unroll
                for (int ch = 0; ch < 2; ++ch) {
                    f32x4 acc[4];
                    #pragma unroll
                    for (int n = 0; n < 4; ++n) {
                        const int ro = roffv[ch * 4 + n];
                        U4F bh; bh.u = *reinterpret_cast<const uint4*>(X + ro);
                        U4F bm; bm.u = *reinterpret_cast<const uint4*>(X + 8192 + ro);
                        U4F bl; bl.u = *reinterpret_cast<const uint4*>(X + 16384 + ro);
                        f32x4 a = __builtin_amdgcn_mfma_f32_16x16x32_bf16(Ah[tl], bl.f, zero4, 0, 0, 0);
                        a = __builtin_amdgcn_mfma_f32_16x16x32_bf16(Al[tl], bh.f, a, 0, 0, 0);
                        a = __builtin_amdgcn_mfma_f32_16x16x32_bf16(Am[tl], bm.f, a, 0, 0, 0);
                        a = __builtin_amdgcn_mfma_f32_16x16x32_bf16(Am[tl], bh.f, a, 0, 0, 0);
                        a = __builtin_amdgcn_mfma_f32_16x16x32_bf16(Ah[tl], bm.f, a, 0, 0, 0);
                        acc[n] = __builtin_amdgcn_mfma_f32_16x16x32_bf16(Ah[tl], bh.f, a, 0, 0, 0);
                    }
                    float p0[4], p1[4], p2[4];
                    #pragma unroll
                    for (int n = 0; n < 4; ++n) {
                        float q0 = 0.f, q1 = 0.f, q2 = 0.f;
                        #pragma unroll
                        for (int r = 0; r < 4; ++r) {
                            const float y = fast_tanh(acc[n][r] + b1s[r]);
                            q0 = fmaf(w2s[0][r], y, q0);
                            q1 = fmaf(w2s[1][r], y, q1);
                            q2 = fmaf(w2s[2][r], y, q2);
                        }
                        p0[n] = q0; p1[n] = q1; p2[n] = q2;
                    }
                    #pragma unroll
                    for (int c3 = 0; c3 < 3; ++c3) {
                        const float* p = (c3 == 0) ? p0 : (c3 == 1) ? p1 : p2;
                        const float own = bb1 ? (bb0 ? p[3] : p[2]) : (bb0 ? p[1] : p[0]);
                        const float x1  = bb1 ? (bb0 ? p[2] : p[3]) : (bb0 ? p[0] : p[1]);
                        const float x2  = bb1 ? (bb0 ? p[1] : p[0]) : (bb0 ? p[3] : p[2]);
                        const float x3  = bb1 ? (bb0 ? p[0] : p[1]) : (bb0 ? p[2] : p[3]);
                        const float a = own + __shfl_xor(x1, 16, 64);
                        const float b = x2  + __shfl_xor(x3, 16, 64);
                        const float T = a + __shfl_xor(b, 32, 64);
                        if (c3 == 0) Z0[ch] = T; else if (c3 == 1) Z1[ch] = T; else Z2[ch] = T;
                    }
                }
            }

            // ---- dynamics + integration + staging for both chains ----
            #pragma unroll
            for (int ch = 0; ch < 2; ++ch) {
                const float4 a01 = av0[ch], a23 = av1[ch];
                const float ax = (tl == 0) ? a01.x : (tl == 1) ? a01.z : (tl == 2) ? a23.x : a23.z;
                const float ay = (tl == 0) ? a01.y : (tl == 1) ? a01.w : (tl == 2) ? a23.y : a23.w;
                AX[ch] = ax; AY[ch] = ay;

                const float rev = S4[ch] * INV2PI;
                const float sn = __builtin_amdgcn_sinf(rev);
                const float c  = __builtin_amdgcn_cosf(rev);

                const float Vx = S1[ch] * c + S3[ch] * sn;
                const float v3 = c * S3[ch] - sn * S1[ch];
                const float v5 = S5[ch];

                const float inv_mvx  = __builtin_amdgcn_rcpf(MF * Vx);
                const float inv_izvx = __builtin_amdgcn_rcpf(IZF * Vx);
                const float a33 = A33N * inv_mvx;
                const float a35 = -Vx + A35N * inv_mvx;
                const float a53 = A53N * inv_izvx;
                const float a55 = A55N * inv_izvx;

                const float d0 = Vx;
                float       d1 = (TH[ch] - THR_OFF) * THR_RAT;
                const float d2 = v3;
                float       d3 = a33 * v3 + a35 * v5 + ST1 * SR[ch];
                const float d4 = v5;
                float       d5 = a53 * v3 + a55 * v5 + ST5 * SR[ch];

                if (rnn) {
                    d1 += fast_tanh(Z0[ch] + bias2_0) * R0M;
                    d3 += fast_tanh(Z1[ch] + bias2_1) * R1M;
                    d5 += fast_tanh(Z2[ch] + bias2_2) * R2I;
                }

                const float ns0 = S0[ch] + (c * d0 - sn * d2) * DT;
                const float ns1 = S1[ch] + (c * d1 - sn * d3) * DT;
                const float ns2 = S2[ch] + (sn * d0 + c * d2) * DT;
                const float ns3 = S3[ch] + (sn * d1 + c * d3) * DT;
                float aa = S4[ch] + d4 * DT + PI_F;
                aa = aa - floorf(aa * INV2PI) * TWOPI;
                const float ns4 = aa - PI_F;
                const float ns5 = S5[ch] + d5 * DT;

                const int e = ch * 64 + L;
                const int c4b = (tl & 1) * 2;
                *reinterpret_cast<float4*>(&sbuf[e * 16 + 4 * ((c4b + 0) ^ (L & 3))]) =
                    make_float4(ns0, ns1, ns2, ns3);
                *reinterpret_cast<float4*>(&sbuf[e * 16 + 4 * ((c4b + 1) ^ (L & 3))]) =
                    make_float4(ns4, ns5, ax, ay);

                if (rnn) {
                    split3_store(X, wboff[ch] ^ (tl * 16), ns0, ns1, ns2, ns3, ns4, ns5, ax, ay);
                }

                S0[ch] = ns0; S1[ch] = ns1; S2[ch] = ns2; S3[ch] = ns3;
                S4[ch] = ns4; S5[ch] = ns5; TH[ch] = ax;  SR[ch] = ay;
            }

            // ---- flush 2-step chunk (64 B/elem, 8 float4 per lane) ----
            if (tl & 1) {
                const int t2 = tc + tl - 1;
                #pragma unroll
                for (int k = 0; k < 8; ++k) {
                    const int q   = k * 64 + L;
                    const int row = q >> 2;
                    const int f   = q & 3;
                    const float4 v = *reinterpret_cast<const float4*>(
                        &sbuf[row * 16 + 4 * (f ^ (row & 3))]);
                    *reinterpret_cast<float4*>(&out[(blk + row) * 256 + t2 * 8 + f * 4]) = v;
                }
            }
        }
    }
}

} // namespace

extern "C" void kernel_launch(void* const* d_in, const int* in_sizes, int n_in,
                              void* d_out, int out_size, void* d_ws, size_t ws_size,
                              hipStream_t stream) {
    const float* fs = (const float*)d_in[0];
    const float* ac = (const float*)d_in[1];
    const float* w1 = (const float*)d_in[2];
    const float* b1 = (const float*)d_in[3];
    const float* w2 = (const float*)d_in[4];
    const float* b2 = (const float*)d_in[5];
    const int*   en = (const int*)d_in[6];
    float* out = (float*)d_out;
    unsigned* ws = (unsigned*)d_ws;

    hipLaunchKernelGGL(prep_kernel, dim3(1), dim3(256), 0, stream, w1, ws);

    dim3 grid(B_TOTAL / EPW), block(64);
    hipLaunchKernelGGL(rollout_kernel, grid, block, 0, stream,
                       fs, ac, ws, b1, w2, b2, en, out);
}

// Round 18
// 82.860 us; speedup vs baseline: 1.0681x; 1.0236x over previous
//
#include <hip/hip_runtime.h>
#include <math.h>

namespace {

typedef short  bf16x8 __attribute__((ext_vector_type(8)));
typedef float  f32x4  __attribute__((ext_vector_type(4)));

constexpr int B_TOTAL = 131072;
constexpr int T_STEPS = 32;

constexpr double dG   = 9.81;
constexpr double dM   = 0.1667;
constexpr double dCAF = 5.0 * 0.25 * dM * dG;
constexpr double dCAR = dCAF;
constexpr double dLF  = 0.09 - 0.036;
constexpr double dLR  = 0.036;
constexpr double dIZ  = 0.000267;

constexpr float A33N = (float)(-(2.0 * dCAF + 2.0 * dCAR));
constexpr float A35N = (float)(-(2.0 * dCAF * dLF - 2.0 * dCAR * dLR));
constexpr float A53N = (float)(-(2.0 * dLF * dCAF - 2.0 * dLR * dCAR));
constexpr float A55N = (float)(-(2.0 * dLF * dLF * dCAF + 2.0 * dLR * dLR * dCAR));
constexpr float ST1  = (float)(2.0 * dCAF / dM);
constexpr float ST5  = (float)(2.0 * dLF * dCAF / dIZ);
constexpr float MF   = (float)dM;
constexpr float IZF  = (float)dIZ;
constexpr float R0M  = (float)(0.05 * dG / dM);
constexpr float R1M  = (float)(0.05 * dG / dM);
constexpr float R2I  = (float)(0.05 * dG * 0.2 / dIZ);
constexpr float THR_OFF = 0.24f;
constexpr float THR_RAT = 6.98f;
constexpr float DT    = 0.01f;
constexpr float PI_F  = (float)3.14159265358979323846;
constexpr float TWOPI = (float)(2.0 * 3.14159265358979323846);
constexpr float INV2PI = (float)(1.0 / (2.0 * 3.14159265358979323846));
constexpr float TWO_LOG2E = 2.8853900817779268f;

__device__ __forceinline__ float fast_tanh(float x) {
    const float e = __builtin_amdgcn_exp2f(x * TWO_LOG2E);
    return fmaf(-2.0f, __builtin_amdgcn_rcpf(e + 1.0f), 1.0f);
}

__device__ __forceinline__ unsigned bf16_rne_u(float f) {
    unsigned u = __float_as_uint(f);
    return (u + 0x7fffu + ((u >> 16) & 1u)) >> 16;
}

__device__ __forceinline__ unsigned pk_bf16(float lo, float hi) {
    unsigned r;
    asm("v_cvt_pk_bf16_f32 %0, %1, %2" : "=v"(r) : "v"(lo), "v"(hi));
    return r;
}
__device__ __forceinline__ float bfl(unsigned p) { return __uint_as_float(p << 16); }
__device__ __forceinline__ float bfh(unsigned p) { return __uint_as_float(p & 0xffff0000u); }

union U4F { uint4 u; bf16x8 f; };

// ---- prep: A-fragments (W1 16x32) for 4 rotations x 3 split levels.
__global__ void prep_kernel(const float* __restrict__ w1, unsigned* __restrict__ ws) {
    const int i = threadIdx.x;
    if (i >= 256) return;
    const int p = i >> 6, L = i & 63;
    const int row = L & 15, g = L >> 4;
    const int pos = (g - p) & 3;
    unsigned hd[4], md[4], ld[4];
    #pragma unroll
    for (int d = 0; d < 4; ++d) {
        unsigned hh[2], mm[2], ll[2];
        #pragma unroll
        for (int s = 0; s < 2; ++s) {
            const float v = w1[row * 32 + pos * 8 + 2 * d + s];
            const unsigned h = bf16_rne_u(v);
            const float r1 = v - __uint_as_float(h << 16);
            const unsigned m = bf16_rne_u(r1);
            const float r2 = r1 - __uint_as_float(m << 16);
            const unsigned l = bf16_rne_u(r2);
            hh[s] = h; mm[s] = m; ll[s] = l;
        }
        hd[d] = hh[0] | (hh[1] << 16);
        md[d] = mm[0] | (mm[1] << 16);
        ld[d] = ll[0] | (ll[1] << 16);
    }
    uint4* w4 = reinterpret_cast<uint4*>(ws);
    w4[(p * 3 + 0) * 64 + L] = make_uint4(hd[0], hd[1], hd[2], hd[3]);
    w4[(p * 3 + 1) * 64 + L] = make_uint4(md[0], md[1], md[2], md[3]);
    w4[(p * 3 + 2) * 64 + L] = make_uint4(ld[0], ld[1], ld[2], ld[3]);
}

__device__ __forceinline__ int xbase(int e) { return (e * 64) ^ ((e & 7) << 4); }

// 3-level split of one timestep row (8 f32) -> X (hi +0, mid +4096, lo +8192)
__device__ __forceinline__ void split3_store(
    char* X, int off,
    float v0, float v1, float v2, float v3, float v4, float v5, float v6, float v7)
{
    const unsigned h0 = pk_bf16(v0, v1), h1 = pk_bf16(v2, v3);
    const unsigned h2 = pk_bf16(v4, v5), h3 = pk_bf16(v6, v7);
    const float r0 = v0 - bfl(h0), r1 = v1 - bfh(h0);
    const float r2 = v2 - bfl(h1), r3 = v3 - bfh(h1);
    const float r4 = v4 - bfl(h2), r5 = v5 - bfh(h2);
    const float r6 = v6 - bfl(h3), r7 = v7 - bfh(h3);
    const unsigned m0 = pk_bf16(r0, r1), m1 = pk_bf16(r2, r3);
    const unsigned m2 = pk_bf16(r4, r5), m3 = pk_bf16(r6, r7);
    const unsigned l0 = pk_bf16(r0 - bfl(m0), r1 - bfh(m0));
    const unsigned l1 = pk_bf16(r2 - bfl(m1), r3 - bfh(m1));
    const unsigned l2 = pk_bf16(r4 - bfl(m2), r5 - bfh(m2));
    const unsigned l3 = pk_bf16(r6 - bfl(m3), r7 - bfh(m3));
    *reinterpret_cast<uint4*>(X + off)        = make_uint4(h0, h1, h2, h3);
    *reinterpret_cast<uint4*>(X + 4096 + off) = make_uint4(m0, m1, m2, m3);
    *reinterpret_cast<uint4*>(X + 8192 + off) = make_uint4(l0, l1, l2, l3);
}

__global__ __launch_bounds__(64, 2)
void rollout_kernel(const float* __restrict__ fs,     // B x 4 x 8
                    const float* __restrict__ acts,   // B x 32 x 2
                    const unsigned* __restrict__ ws,  // A-fragments (prep)
                    const float* __restrict__ b1g,    // 16
                    const float* __restrict__ w2g,    // 3 x 16
                    const float* __restrict__ b2g,    // 3
                    const int*   __restrict__ en,     // 1
                    float*       __restrict__ out)    // B x 32 x 8
{
    __shared__ char  X[12288];            // 12 KB window: hi | mid | lo
    __shared__ float abuf[64 * 8];        // 2 KB  actions, 4 steps
    __shared__ float sbuf[64 * 16];       // 4 KB  outputs, 2 steps
    // total 18 KB -> 8 single-wave blocks/CU

    const int L = threadIdx.x;            // lane = owned element
    const int g = L >> 4;                 // k-group / D-row-group
    const size_t blk = (size_t)blockIdx.x * 64;

    const int rnn = *en;

    // ---- loop-invariant registers ----
    bf16x8 Ah[4], Am[4], Al[4];
    {
        const uint4* w4 = reinterpret_cast<const uint4*>(ws);
        #pragma unroll
        for (int p = 0; p < 4; ++p) {
            U4F a; a.u = w4[(p * 3 + 0) * 64 + L]; Ah[p] = a.f;
            U4F b; b.u = w4[(p * 3 + 1) * 64 + L]; Am[p] = b.f;
            U4F c; c.u = w4[(p * 3 + 2) * 64 + L]; Al[p] = c.f;
        }
    }
    float b1s[4];
    #pragma unroll
    for (int r = 0; r < 4; ++r) b1s[r] = b1g[g * 4 + r];
    float w2s[3][4];
    #pragma unroll
    for (int c = 0; c < 3; ++c)
        #pragma unroll
        for (int r = 0; r < 4; ++r) w2s[c][r] = w2g[c * 16 + g * 4 + r];
    const float bias2_0 = b2g[0], bias2_1 = b2g[1], bias2_2 = b2g[2];

    // hoisted LDS offsets
    int roffv[4];
    #pragma unroll
    for (int n = 0; n < 4; ++n) roffv[n] = xbase(16 * n + (L & 15)) ^ (g * 16);
    const int wboff = xbase(L);

    // action staging addresses (lane-fixed)
    const int q0r = L >> 1,        q0f = (L & 1) * 4;          // k=0
    const int q1r = (64 + L) >> 1, q1f = (L & 1) * 4;          // k=1
    const int aw0 = q0r * 8 + (q0f ^ (q0r & 4));
    const int aw1 = q1r * 8 + (q1f ^ (q1r & 4));

    // ---- init: own element's 4 history rows -> X tiles + state regs ----
    float s0, s1, s2, s3, s4, s5, thr, steer;
    {
        const float4* ip = reinterpret_cast<const float4*>(fs + (blk + L) * 32);
        #pragma unroll
        for (int rr = 0; rr < 4; ++rr) {
            const float4 va = ip[rr * 2], vb = ip[rr * 2 + 1];
            split3_store(X, wboff ^ (rr * 16), va.x, va.y, va.z, va.w, vb.x, vb.y, vb.z, vb.w);
            if (rr == 3) {
                s0 = va.x; s1 = va.y; s2 = va.z; s3 = va.w;
                s4 = vb.x; s5 = vb.y; thr = vb.z; steer = vb.w;
            }
        }
    }

    // software-pipelined B-fragment buffers (window reads for the NEXT step)
    U4F BH[4], BM[4], BL[4];
    #pragma unroll
    for (int n = 0; n < 4; ++n) {
        BH[n].u = *reinterpret_cast<const uint4*>(X + roffv[n]);
        BM[n].u = *reinterpret_cast<const uint4*>(X + 4096 + roffv[n]);
        BL[n].u = *reinterpret_cast<const uint4*>(X + 8192 + roffv[n]);
    }

    // prologue: issue chunk-0 action loads (coalesced pairs)
    float4 ga0 = *reinterpret_cast<const float4*>(&acts[(blk + q0r) * 64 + q0f]);
    float4 ga1 = *reinterpret_cast<const float4*>(&acts[(blk + q1r) * 64 + q1f]);

    const f32x4 zero4 = {0.f, 0.f, 0.f, 0.f};

    for (int tc = 0; tc < T_STEPS; tc += 4) {
        // ---- stage the in-flight action data, read own 4 steps to regs ----
        *reinterpret_cast<float4*>(&abuf[aw0]) = ga0;
        *reinterpret_cast<float4*>(&abuf[aw1]) = ga1;
        const float4 av0 = *reinterpret_cast<const float4*>(&abuf[L * 8 + (0 ^ (L & 4))]);
        const float4 av1 = *reinterpret_cast<const float4*>(&abuf[L * 8 + (4 ^ (L & 4))]);
        // issue next chunk's loads (latency hidden under 4 steps of compute)
        if (tc + 4 < T_STEPS) {
            ga0 = *reinterpret_cast<const float4*>(&acts[(blk + q0r) * 64 + (tc + 4) * 2 + q0f]);
            ga1 = *reinterpret_cast<const float4*>(&acts[(blk + q1r) * 64 + (tc + 4) * 2 + q1f]);
        }

        #pragma unroll
        for (int tl = 0; tl < 4; ++tl) {
            const float ax = (tl == 0) ? av0.x : (tl == 1) ? av0.z : (tl == 2) ? av1.x : av1.z;
            const float ay = (tl == 0) ? av0.y : (tl == 1) ? av0.w : (tl == 2) ? av1.y : av1.w;

            // raw HW sin/cos (input in revolutions; psi in [-pi,pi] -> in range)
            const float rev = s4 * INV2PI;
            const float sn = __builtin_amdgcn_sinf(rev);
            const float c  = __builtin_amdgcn_cosf(rev);

            const float Vx = s1 * c + s3 * sn;
            const float v3 = c * s3 - sn * s1;
            const float v5 = s5;

            const float inv_mvx  = __builtin_amdgcn_rcpf(MF * Vx);
            const float inv_izvx = __builtin_amdgcn_rcpf(IZF * Vx);
            const float a33 = A33N * inv_mvx;
            const float a35 = -Vx + A35N * inv_mvx;
            const float a53 = A53N * inv_izvx;
            const float a55 = A55N * inv_izvx;

            const float d0 = Vx;
            float       d1 = (thr - THR_OFF) * THR_RAT;
            const float d2 = v3;
            float       d3 = a33 * v3 + a35 * v5 + ST1 * steer;
            const float d4 = v5;
            float       d5 = a53 * v3 + a55 * v5 + ST5 * steer;

            float z0, z1, z2;
            if (rnn) {
                // ---- layer 1 via MFMA, 3-level compensated; two independent
                //      3-chains (small terms | big terms) + one f32x4 add ----
                f32x4 acc[4];
                #pragma unroll
                for (int n = 0; n < 4; ++n) {
                    f32x4 sm = __builtin_amdgcn_mfma_f32_16x16x32_bf16(Ah[tl], BL[n].f, zero4, 0, 0, 0);
                    sm = __builtin_amdgcn_mfma_f32_16x16x32_bf16(Al[tl], BH[n].f, sm, 0, 0, 0);
                    sm = __builtin_amdgcn_mfma_f32_16x16x32_bf16(Am[tl], BM[n].f, sm, 0, 0, 0);
                    f32x4 bg = __builtin_amdgcn_mfma_f32_16x16x32_bf16(Am[tl], BH[n].f, zero4, 0, 0, 0);
                    bg = __builtin_amdgcn_mfma_f32_16x16x32_bf16(Ah[tl], BM[n].f, bg, 0, 0, 0);
                    bg = __builtin_amdgcn_mfma_f32_16x16x32_bf16(Ah[tl], BH[n].f, bg, 0, 0, 0);
                    acc[n] = sm + bg;
                }
                float p0[4], p1[4], p2[4];
                #pragma unroll
                for (int n = 0; n < 4; ++n) {
                    float q0 = 0.f, q1 = 0.f, q2 = 0.f;
                    #pragma unroll
                    for (int r = 0; r < 4; ++r) {
                        const float y = fast_tanh(acc[n][r] + b1s[r]);
                        q0 = fmaf(w2s[0][r], y, q0);
                        q1 = fmaf(w2s[1][r], y, q1);
                        q2 = fmaf(w2s[2][r], y, q2);
                    }
                    p0[n] = q0; p1[n] = q1; p2[n] = q2;
                }
                const bool bb0 = (g & 1) != 0, bb1 = (g & 2) != 0;
                #pragma unroll
                for (int c3 = 0; c3 < 3; ++c3) {
                    const float* p = (c3 == 0) ? p0 : (c3 == 1) ? p1 : p2;
                    const float own = bb1 ? (bb0 ? p[3] : p[2]) : (bb0 ? p[1] : p[0]);
                    const float x1  = bb1 ? (bb0 ? p[2] : p[3]) : (bb0 ? p[0] : p[1]);
                    const float x2  = bb1 ? (bb0 ? p[1] : p[0]) : (bb0 ? p[3] : p[2]);
                    const float x3  = bb1 ? (bb0 ? p[0] : p[1]) : (bb0 ? p[2] : p[3]);
                    const float a = own + __shfl_xor(x1, 16, 64);
                    const float b = x2  + __shfl_xor(x3, 16, 64);
                    const float T = a + __shfl_xor(b, 32, 64);
                    if (c3 == 0) z0 = T; else if (c3 == 1) z1 = T; else z2 = T;
                }
                d1 += fast_tanh(z0 + bias2_0) * R0M;
                d3 += fast_tanh(z1 + bias2_1) * R1M;
                d5 += fast_tanh(z2 + bias2_2) * R2I;
            }

            const float ns0 = s0 + (c * d0 - sn * d2) * DT;
            const float ns1 = s1 + (c * d1 - sn * d3) * DT;
            const float ns2 = s2 + (sn * d0 + c * d2) * DT;
            const float ns3 = s3 + (sn * d1 + c * d3) * DT;
            float aa = s4 + d4 * DT + PI_F;
            aa = aa - floorf(aa * INV2PI) * TWOPI;
            const float ns4 = aa - PI_F;
            const float ns5 = s5 + d5 * DT;

            // stage outputs (elem-major, xor-swizzled float4 slots)
            const int c4b = (tl & 1) * 2;
            *reinterpret_cast<float4*>(&sbuf[L * 16 + 4 * ((c4b + 0) ^ (L & 3))]) =
                make_float4(ns0, ns1, ns2, ns3);
            *reinterpret_cast<float4*>(&sbuf[L * 16 + 4 * ((c4b + 1) ^ (L & 3))]) =
                make_float4(ns4, ns5, ax, ay);

            if (rnn) {
                split3_store(X, wboff ^ (tl * 16), ns0, ns1, ns2, ns3, ns4, ns5, ax, ay);
                // software pipeline: issue next step's window reads NOW
                // (same-wave LDS ordering makes them see the write above);
                // ~full dynamics+staging+flush hides the ds_read latency.
                #pragma unroll
                for (int n = 0; n < 4; ++n) {
                    BH[n].u = *reinterpret_cast<const uint4*>(X + roffv[n]);
                    BM[n].u = *reinterpret_cast<const uint4*>(X + 4096 + roffv[n]);
                    BL[n].u = *reinterpret_cast<const uint4*>(X + 8192 + roffv[n]);
                }
            }

            s0 = ns0; s1 = ns1; s2 = ns2; s3 = ns3;
            s4 = ns4; s5 = ns5; thr = ax; steer = ay;

            // ---- flush 2-step chunk (64 B/elem) ----
            if (tl & 1) {
                const int t2 = tc + tl - 1;
                #pragma unroll
                for (int k = 0; k < 4; ++k) {
                    const int q   = k * 64 + L;
                    const int row = q >> 2;
                    const int f   = q & 3;
                    const float4 v = *reinterpret_cast<const float4*>(
                        &sbuf[row * 16 + 4 * (f ^ (row & 3))]);
                    *reinterpret_cast<float4*>(&out[(blk + row) * 256 + t2 * 8 + f * 4]) = v;
                }
            }
        }
    }
}

} // namespace

extern "C" void kernel_launch(void* const* d_in, const int* in_sizes, int n_in,
                              void* d_out, int out_size, void* d_ws, size_t ws_size,
                              hipStream_t stream) {
    const float* fs = (const float*)d_in[0];
    const float* ac = (const float*)d_in[1];
    const float* w1 = (const float*)d_in[2];
    const float* b1 = (const float*)d_in[3];
    const float* w2 = (const float*)d_in[4];
    const float* b2 = (const float*)d_in[5];
    const int*   en = (const int*)d_in[6];
    float* out = (float*)d_out;
    unsigned* ws = (unsigned*)d_ws;

    hipLaunchKernelGGL(prep_kernel, dim3(1), dim3(256), 0, stream, w1, ws);

    dim3 grid(B_TOTAL / 64), block(64);
    hipLaunchKernelGGL(rollout_kernel, grid, block, 0, stream,
                       fs, ac, ws, b1, w2, b2, en, out);
}